// Round 2
// baseline (10423.978 us; speedup 1.0000x reference)
//
#include <hip/hip_runtime.h>
#include <hip/hip_bf16.h>
#include <math.h>

// LSTM: S=512, B=64, I=1024, H=1024
// out[S,B,H] fp32, then h_last[B,H], c_last[B,H]
//
//  1) convert x,W_ih,W_hh,h0 -> bf16 in ws
//  2) gates_x[S*B,4H] = x @ W_ih^T  (128x128 MFMA GEMM, bf16 out)
//  3) ONE persistent cooperative kernel runs all 512 steps:
//     64 blocks x 512 thr; block owns 16 h-cols x 4 gates; W_hh frags in
//     registers (loaded once); h handoff via global double-buffer + per-step
//     arrival counters (agent-scope atomics); c state in registers.

#define S_LEN 512
#define BATCH 64
#define IDIM 1024
#define HDIM 1024
#define GDIM 4096

typedef __bf16 bf16x8 __attribute__((ext_vector_type(8)));
typedef float f32x4 __attribute__((ext_vector_type(4)));

__device__ inline ushort f2b(float f) {
    union { float f; unsigned u; } v; v.f = f;
    unsigned u = v.u;
    unsigned r = (u + 0x7fffu + ((u >> 16) & 1u)) >> 16;
    return (ushort)r;
}
__device__ inline float b2f(ushort u) {
    union { unsigned u; float f; } v; v.u = ((unsigned)u) << 16;
    return v.f;
}
__device__ inline float sigmoidf_(float x) { return 1.f / (1.f + __expf(-x)); }
__device__ inline float tanhf_(float x) {
    return 1.f - 2.f / (__expf(2.f * x) + 1.f);
}

// ---------- conversion kernels ----------
__global__ __launch_bounds__(256) void f2b_kernel(ushort* __restrict__ dst,
                                                  const float* __restrict__ src, int n) {
    int i = (blockIdx.x * 256 + threadIdx.x) * 4;
    if (i < n) {
        float4 v = *(const float4*)(src + i);
        ushort4 o;
        o.x = f2b(v.x); o.y = f2b(v.y); o.z = f2b(v.z); o.w = f2b(v.w);
        *(ushort4*)(dst + i) = o;
    }
}

__global__ __launch_bounds__(256) void bias_kernel(float* __restrict__ bias,
                                                   const float* __restrict__ b_ih,
                                                   const float* __restrict__ b_hh) {
    int i = blockIdx.x * 256 + threadIdx.x;
    if (i < GDIM) bias[i] = b_ih[i] + b_hh[i];
}

// ---------- big GEMM: C[M,N] = A[M,K] @ B[N,K]^T ----------
#define LDSS 72
__global__ __launch_bounds__(256) void gemm_bt_kernel(const ushort* __restrict__ A,
                                                      const ushort* __restrict__ B,
                                                      ushort* __restrict__ C,
                                                      int M, int N, int K) {
    __shared__ __align__(16) ushort As[128 * LDSS];
    __shared__ __align__(16) ushort Bs[128 * LDSS];
    const int tid = threadIdx.x;
    const int lane = tid & 63;
    const int wave = tid >> 6;
    const int l15 = lane & 15;
    const int quad = lane >> 4;
    const int bn = blockIdx.x;
    const int bm = blockIdx.y;
    const int wrow = (wave & 1) * 64;
    const int wcol = (wave >> 1) * 64;

    f32x4 acc[4][4] = {};

    for (int kt = 0; kt < K; kt += 64) {
        #pragma unroll
        for (int i = 0; i < 4; i++) {
            int chunk = tid + i * 256;
            int r = chunk >> 3;
            int c8 = (chunk & 7) * 8;
            *(uint4*)&As[r * LDSS + c8] =
                *(const uint4*)&A[(size_t)(bm * 128 + r) * K + kt + c8];
            *(uint4*)&Bs[r * LDSS + c8] =
                *(const uint4*)&B[(size_t)(bn * 128 + r) * K + kt + c8];
        }
        __syncthreads();
        #pragma unroll
        for (int kc = 0; kc < 2; kc++) {
            const int ko = kc * 32 + quad * 8;
            bf16x8 af[4], bf[4];
            #pragma unroll
            for (int m = 0; m < 4; m++)
                af[m] = *(const bf16x8*)&As[(wrow + m * 16 + l15) * LDSS + ko];
            #pragma unroll
            for (int n = 0; n < 4; n++)
                bf[n] = *(const bf16x8*)&Bs[(wcol + n * 16 + l15) * LDSS + ko];
            #pragma unroll
            for (int m = 0; m < 4; m++)
                #pragma unroll
                for (int n = 0; n < 4; n++)
                    acc[m][n] = __builtin_amdgcn_mfma_f32_16x16x32_bf16(af[m], bf[n], acc[m][n], 0, 0, 0);
        }
        __syncthreads();
    }
    const int col0 = bn * 128 + wcol;
    const int row0 = bm * 128 + wrow;
    #pragma unroll
    for (int m = 0; m < 4; m++) {
        #pragma unroll
        for (int n = 0; n < 4; n++) {
            int col = col0 + n * 16 + l15;
            int rbase = row0 + m * 16 + quad * 4;
            #pragma unroll
            for (int r = 0; r < 4; r++)
                C[(size_t)(rbase + r) * N + col] = f2b(acc[m][n][r]);
        }
    }
}

// ---------- persistent recurrence kernel ----------
// 64 blocks x 512 threads (8 waves). Block b owns h-cols [b*16, b*16+16).
// Wave wv: gate = wv&3, mw = wv>>2 (batches mw*32..+32, 2 m-frags).
// W_hh b-frags for full K=1024 held in registers (32 x bf16x8 per wave).
#define HS 264          // LDS h row stride (elements): 2-way-free banks for frags
#define GSB 18          // Gs per-batch stride (floats)

__global__ __launch_bounds__(512) void lstm_persistent(
    const ushort* __restrict__ gx,
    ushort* __restrict__ hb0, ushort* __restrict__ hb1,
    const ushort* __restrict__ Whh,
    const float* __restrict__ bias,
    const float* __restrict__ c0,
    float* __restrict__ out,
    unsigned* __restrict__ cnt)
{
    __shared__ __align__(16) ushort Hs[64 * HS];     // 33,792 B (one 256-K chunk)
    __shared__ float Gs[4 * 64 * GSB];               // 18,432 B

    const int tid = threadIdx.x;
    const int lane = tid & 63;
    const int wv = tid >> 6;
    const int gate = wv & 3;
    const int mw = wv >> 2;
    const int l15 = lane & 15;
    const int quad = lane >> 4;
    const int blk = blockIdx.x;

    // ---- preload W fragments (once) ----
    bf16x8 wf[32];
    {
        const ushort* wrow = Whh + ((size_t)(gate * 1024 + blk * 16 + l15)) * 1024 + quad * 8;
        #pragma unroll
        for (int ks = 0; ks < 32; ks++)
            wf[ks] = *(const bf16x8*)(wrow + ks * 32);
    }

    // ---- pointwise per-thread state: elements (pb, pj) and (pb, pj+1) ----
    const int pb = tid >> 3;              // batch
    const int pj = (tid * 2) & 15;        // even local col
    const int pcol = blk * 16 + pj;       // global h col
    float2 creg = *(const float2*)&c0[(size_t)pb * HDIM + pcol];
    float bsum[4][2];
    #pragma unroll
    for (int g = 0; g < 4; g++) {
        bsum[g][0] = bias[g * 1024 + pcol];
        bsum[g][1] = bias[g * 1024 + pcol + 1];
    }
    const size_t gx_tb = (size_t)pb * GDIM + blk * 16 + pj;

    #pragma unroll 1
    for (int s = 0; s < S_LEN; s++) {
        const ushort* hsrc = (s & 1) ? hb1 : hb0;
        ushort* hdst = (s & 1) ? hb0 : hb1;

        // prefetch gx[s] for this thread's outputs (independent of h)
        ushort2 gxr[4];
        {
            const ushort* gxs = gx + (size_t)s * BATCH * GDIM + gx_tb;
            #pragma unroll
            for (int g = 0; g < 4; g++)
                gxr[g] = *(const ushort2*)(gxs + g * 1024);
        }

        // wait for h_s to be published by all producers
        if (s > 0) {
            if (tid == 0) {
                while (__hip_atomic_load(&cnt[s], __ATOMIC_ACQUIRE, __HIP_MEMORY_SCOPE_AGENT) < 64u)
                    __builtin_amdgcn_s_sleep(1);
                __threadfence();   // agent acquire: invalidate stale L1/L2
            }
            __syncthreads();
        }

        f32x4 acc0 = {0.f, 0.f, 0.f, 0.f};
        f32x4 acc1 = {0.f, 0.f, 0.f, 0.f};

        // register-prefetch chunk 0 (64 rows x 256 cols bf16 = 32 KiB)
        uint4 rbuf[4];
        #pragma unroll
        for (int i = 0; i < 4; i++) {
            int gidx = tid + i * 512;
            int row = gidx >> 5, cg = gidx & 31;
            rbuf[i] = *(const uint4*)(hsrc + (size_t)row * HDIM + cg * 8);
        }

        #pragma unroll
        for (int c = 0; c < 4; c++) {
            __syncthreads();   // Hs free (prev chunk's MFMA reads done)
            #pragma unroll
            for (int i = 0; i < 4; i++) {
                int gidx = tid + i * 512;
                int row = gidx >> 5, cg = gidx & 31;
                *(uint4*)&Hs[row * HS + cg * 8] = rbuf[i];
            }
            __syncthreads();
            if (c < 3) {   // async prefetch next chunk while MFMA runs
                #pragma unroll
                for (int i = 0; i < 4; i++) {
                    int gidx = tid + i * 512;
                    int row = gidx >> 5, cg = gidx & 31;
                    rbuf[i] = *(const uint4*)(hsrc + (size_t)row * HDIM + (c + 1) * 256 + cg * 8);
                }
            }
            #pragma unroll
            for (int k8 = 0; k8 < 8; k8++) {
                const int ko = k8 * 32 + quad * 8;
                bf16x8 a0 = *(const bf16x8*)&Hs[(mw * 32 + l15) * HS + ko];
                bf16x8 a1 = *(const bf16x8*)&Hs[(mw * 32 + 16 + l15) * HS + ko];
                acc0 = __builtin_amdgcn_mfma_f32_16x16x32_bf16(a0, wf[c * 8 + k8], acc0, 0, 0, 0);
                acc1 = __builtin_amdgcn_mfma_f32_16x16x32_bf16(a1, wf[c * 8 + k8], acc1, 0, 0, 0);
            }
        }

        // exchange gates through LDS (C layout: col=lane&15, row=quad*4+reg)
        #pragma unroll
        for (int f = 0; f < 2; f++) {
            f32x4 a = f ? acc1 : acc0;
            int b0 = mw * 32 + f * 16 + quad * 4;
            #pragma unroll
            for (int r = 0; r < 4; r++)
                Gs[gate * (64 * GSB) + (b0 + r) * GSB + l15] = a[r];
        }
        __syncthreads();

        // pointwise: 2 elements per thread
        float hv[2], cv[2];
        #pragma unroll
        for (int u = 0; u < 2; u++) {
            float cold = u ? creg.y : creg.x;
            float g0 = Gs[0 * 64 * GSB + pb * GSB + pj + u] + bsum[0][u] + b2f(u ? gxr[0].y : gxr[0].x);
            float g1 = Gs[1 * 64 * GSB + pb * GSB + pj + u] + bsum[1][u] + b2f(u ? gxr[1].y : gxr[1].x);
            float g2 = Gs[2 * 64 * GSB + pb * GSB + pj + u] + bsum[2][u] + b2f(u ? gxr[2].y : gxr[2].x);
            float g3 = Gs[3 * 64 * GSB + pb * GSB + pj + u] + bsum[3][u] + b2f(u ? gxr[3].y : gxr[3].x);
            float ig = sigmoidf_(g0);
            float fg = sigmoidf_(g1);
            float gg = tanhf_(g2);
            float og = sigmoidf_(g3);
            float cn = fg * cold + ig * gg;
            float hn = og * tanhf_(cn);
            cv[u] = cn; hv[u] = hn;
        }
        creg.x = cv[0]; creg.y = cv[1];

        float2 ho; ho.x = hv[0]; ho.y = hv[1];
        *(float2*)&out[(size_t)s * BATCH * HDIM + (size_t)pb * HDIM + pcol] = ho;
        ushort2 hb; hb.x = f2b(hv[0]); hb.y = f2b(hv[1]);
        *(ushort2*)&hdst[(size_t)pb * HDIM + pcol] = hb;

        if (s == S_LEN - 1) {
            float* tail = out + (size_t)S_LEN * BATCH * HDIM;
            *(float2*)&tail[(size_t)pb * HDIM + pcol] = ho;
            float2 co; co.x = cv[0]; co.y = cv[1];
            *(float2*)&tail[BATCH * HDIM + (size_t)pb * HDIM + pcol] = co;
        }

        // publish h_{s+1}: barrier drains all waves' stores (vmcnt0 before
        // s_barrier), release-add writes back L2 so other XCDs see fresh h
        __syncthreads();
        if (tid == 0) {
            __threadfence();
            __hip_atomic_fetch_add(&cnt[s + 1], 1u, __ATOMIC_RELEASE, __HIP_MEMORY_SCOPE_AGENT);
        }
    }
}

extern "C" void kernel_launch(void* const* d_in, const int* in_sizes, int n_in,
                              void* d_out, int out_size, void* d_ws, size_t ws_size,
                              hipStream_t stream) {
    const float* x    = (const float*)d_in[0];
    const float* h0   = (const float*)d_in[1];
    const float* c0   = (const float*)d_in[2];
    const float* W_ih = (const float*)d_in[3];
    const float* b_ih = (const float*)d_in[4];
    const float* W_hh = (const float*)d_in[5];
    const float* b_hh = (const float*)d_in[6];
    float* out = (float*)d_out;

    const size_t n_x  = (size_t)S_LEN * BATCH * IDIM;
    const size_t n_w  = (size_t)GDIM * IDIM;
    const size_t o_xb   = 0;
    const size_t o_gx   = o_xb + n_x * 2;
    const size_t o_wih  = o_gx + (size_t)S_LEN * BATCH * GDIM * 2;
    const size_t o_whh  = o_wih + n_w * 2;
    const size_t o_bias = o_whh + n_w * 2;
    const size_t o_h0   = o_bias + GDIM * 4;
    const size_t o_h1   = o_h0 + (size_t)BATCH * HDIM * 2;
    const size_t o_cnt  = o_h1 + (size_t)BATCH * HDIM * 2;
    const size_t total  = o_cnt + 4096;
    if (ws_size < total) return;

    char* ws = (char*)d_ws;
    ushort* xb   = (ushort*)(ws + o_xb);
    ushort* gx   = (ushort*)(ws + o_gx);
    ushort* wihb = (ushort*)(ws + o_wih);
    ushort* whhb = (ushort*)(ws + o_whh);
    float*  bias = (float*)(ws + o_bias);
    ushort* hb0  = (ushort*)(ws + o_h0);
    ushort* hb1  = (ushort*)(ws + o_h1);
    unsigned* cnt = (unsigned*)(ws + o_cnt);

    // conversions + bias + flag reset
    f2b_kernel<<<(int)(n_x / 1024), 256, 0, stream>>>(xb, x, (int)n_x);
    f2b_kernel<<<(int)(n_w / 1024), 256, 0, stream>>>(wihb, W_ih, (int)n_w);
    f2b_kernel<<<(int)(n_w / 1024), 256, 0, stream>>>(whhb, W_hh, (int)n_w);
    f2b_kernel<<<(BATCH * HDIM) / 1024, 256, 0, stream>>>(hb0, h0, BATCH * HDIM);
    bias_kernel<<<GDIM / 256, 256, 0, stream>>>(bias, b_ih, b_hh);
    hipMemsetAsync(cnt, 0, (S_LEN + 1) * sizeof(unsigned), stream);

    // gates_x = x @ W_ih^T  (M=32768, N=4096, K=1024)
    {
        dim3 grid(GDIM / 128, (S_LEN * BATCH) / 128);
        gemm_bt_kernel<<<grid, 256, 0, stream>>>(xb, wihb, gx, S_LEN * BATCH, GDIM, IDIM);
    }

    // persistent recurrence (cooperative: all 64 blocks co-resident)
    {
        const ushort* gx_c = gx;
        const ushort* whh_c = whhb;
        const float* bias_c = bias;
        void* args[] = { (void*)&gx_c, (void*)&hb0, (void*)&hb1, (void*)&whh_c,
                         (void*)&bias_c, (void*)&c0, (void*)&out, (void*)&cnt };
        hipLaunchCooperativeKernel((const void*)lstm_persistent, dim3(64), dim3(512),
                                   args, 0, stream);
    }
}

// Round 3
// 4205.627 us; speedup vs baseline: 2.4786x; 2.4786x over previous
//
#include <hip/hip_runtime.h>
#include <hip/hip_bf16.h>
#include <math.h>

// LSTM: S=512, B=64, I=1024, H=1024
// out[S,B,H] fp32, then h_last[B,H], c_last[B,H]
//
//  1) convert x,W_ih,W_hh,h0 -> bf16 in ws
//  2) gates_x[S*B,4H] = x @ W_ih^T  (128x128 MFMA GEMM, bf16 out)
//  3) ONE persistent cooperative kernel runs all 512 steps.
//     Sync design (R3): NO threadfence/acquire fences (they emit
//     buffer_inv/buffer_wbl2 -> L2 nuke storms, R2's 19us/step).
//     Instead every cross-block access is individually coherent (sc1 via
//     RELAXED+AGENT hip atomics): h stores write through to IF/L3, h loads
//     read IF/L3 directly, per-block flags polled with one wave-wide load.

#define S_LEN 512
#define BATCH 64
#define IDIM 1024
#define HDIM 1024
#define GDIM 4096
#define MAGIC 0x1337BEEFu

typedef __bf16 bf16x8 __attribute__((ext_vector_type(8)));
typedef float f32x4 __attribute__((ext_vector_type(4)));

__device__ inline ushort f2b(float f) {
    union { float f; unsigned u; } v; v.f = f;
    unsigned u = v.u;
    unsigned r = (u + 0x7fffu + ((u >> 16) & 1u)) >> 16;
    return (ushort)r;
}
__device__ inline float b2f(ushort u) {
    union { unsigned u; float f; } v; v.u = ((unsigned)u) << 16;
    return v.f;
}
__device__ inline float sigmoidf_(float x) { return 1.f / (1.f + __expf(-x)); }
__device__ inline float tanhf_(float x) {
    return 1.f - 2.f / (__expf(2.f * x) + 1.f);
}

// ---------- conversion kernels ----------
__global__ __launch_bounds__(256) void f2b_kernel(ushort* __restrict__ dst,
                                                  const float* __restrict__ src, int n) {
    int i = (blockIdx.x * 256 + threadIdx.x) * 4;
    if (i < n) {
        float4 v = *(const float4*)(src + i);
        ushort4 o;
        o.x = f2b(v.x); o.y = f2b(v.y); o.z = f2b(v.z); o.w = f2b(v.w);
        *(ushort4*)(dst + i) = o;
    }
}

__global__ __launch_bounds__(256) void bias_kernel(float* __restrict__ bias,
                                                   const float* __restrict__ b_ih,
                                                   const float* __restrict__ b_hh) {
    int i = blockIdx.x * 256 + threadIdx.x;
    if (i < GDIM) bias[i] = b_ih[i] + b_hh[i];
}

// ---------- big GEMM: C[M,N] = A[M,K] @ B[N,K]^T ----------
#define LDSS 72
__global__ __launch_bounds__(256) void gemm_bt_kernel(const ushort* __restrict__ A,
                                                      const ushort* __restrict__ B,
                                                      ushort* __restrict__ C,
                                                      int M, int N, int K) {
    __shared__ __align__(16) ushort As[128 * LDSS];
    __shared__ __align__(16) ushort Bs[128 * LDSS];
    const int tid = threadIdx.x;
    const int lane = tid & 63;
    const int wave = tid >> 6;
    const int l15 = lane & 15;
    const int quad = lane >> 4;
    const int bn = blockIdx.x;
    const int bm = blockIdx.y;
    const int wrow = (wave & 1) * 64;
    const int wcol = (wave >> 1) * 64;

    f32x4 acc[4][4] = {};

    for (int kt = 0; kt < K; kt += 64) {
        #pragma unroll
        for (int i = 0; i < 4; i++) {
            int chunk = tid + i * 256;
            int r = chunk >> 3;
            int c8 = (chunk & 7) * 8;
            *(uint4*)&As[r * LDSS + c8] =
                *(const uint4*)&A[(size_t)(bm * 128 + r) * K + kt + c8];
            *(uint4*)&Bs[r * LDSS + c8] =
                *(const uint4*)&B[(size_t)(bn * 128 + r) * K + kt + c8];
        }
        __syncthreads();
        #pragma unroll
        for (int kc = 0; kc < 2; kc++) {
            const int ko = kc * 32 + quad * 8;
            bf16x8 af[4], bf[4];
            #pragma unroll
            for (int m = 0; m < 4; m++)
                af[m] = *(const bf16x8*)&As[(wrow + m * 16 + l15) * LDSS + ko];
            #pragma unroll
            for (int n = 0; n < 4; n++)
                bf[n] = *(const bf16x8*)&Bs[(wcol + n * 16 + l15) * LDSS + ko];
            #pragma unroll
            for (int m = 0; m < 4; m++)
                #pragma unroll
                for (int n = 0; n < 4; n++)
                    acc[m][n] = __builtin_amdgcn_mfma_f32_16x16x32_bf16(af[m], bf[n], acc[m][n], 0, 0, 0);
        }
        __syncthreads();
    }
    const int col0 = bn * 128 + wcol;
    const int row0 = bm * 128 + wrow;
    #pragma unroll
    for (int m = 0; m < 4; m++) {
        #pragma unroll
        for (int n = 0; n < 4; n++) {
            int col = col0 + n * 16 + l15;
            int rbase = row0 + m * 16 + quad * 4;
            #pragma unroll
            for (int r = 0; r < 4; r++)
                C[(size_t)(rbase + r) * N + col] = f2b(acc[m][n][r]);
        }
    }
}

// ---------- persistent recurrence kernel ----------
// 64 blocks x 512 threads (8 waves). Block b owns h-cols [b*16, b*16+16).
// Wave wv: gate = wv&3, mw = wv>>2 (batches mw*32..+32, 2 m-frags).
// W_hh b-frags for full K=1024 in registers (32 x bf16x8 = 128 VGPR/wave).
// Full h (64x1024 bf16) staged in LDS once per step.
#define HS2 1032        // Hs row stride in elems: 2064B -> conflict-floor b128 reads
#define GSB 18          // Gs per-batch stride (floats)

__global__ __launch_bounds__(512, 2) void lstm_persistent(
    const ushort* __restrict__ gx,
    ushort* __restrict__ hb0, ushort* __restrict__ hb1,
    const ushort* __restrict__ Whh,
    const float* __restrict__ bias,
    const float* __restrict__ c0,
    float* __restrict__ out,
    unsigned* __restrict__ flags)
{
    __shared__ __align__(16) ushort Hs[64 * HS2];    // 132,096 B
    __shared__ float Gs[4 * 64 * GSB];               //  18,432 B

    const int tid = threadIdx.x;
    const int lane = tid & 63;
    const int wv = tid >> 6;
    const int gate = wv & 3;
    const int mw = wv >> 2;
    const int l15 = lane & 15;
    const int quad = lane >> 4;
    const int blk = blockIdx.x;

    // ---- preload W fragments (once): B-frag rows gate*1024+blk*16+l15 ----
    bf16x8 wf[32];
    {
        const ushort* wrow = Whh + ((size_t)(gate * 1024 + blk * 16 + l15)) * 1024 + quad * 8;
        #pragma unroll
        for (int ks = 0; ks < 32; ks++)
            wf[ks] = *(const bf16x8*)(wrow + ks * 32);
    }

    // ---- pointwise per-thread state: elements (pb, pj) and (pb, pj+1) ----
    const int pb = tid >> 3;
    const int pj = (tid * 2) & 15;
    const int pcol = blk * 16 + pj;
    float2 creg = *(const float2*)&c0[(size_t)pb * HDIM + pcol];
    float bsum[4][2];
    #pragma unroll
    for (int g = 0; g < 4; g++) {
        bsum[g][0] = bias[g * 1024 + pcol];
        bsum[g][1] = bias[g * 1024 + pcol + 1];
    }
    const size_t gx_tb = (size_t)pb * GDIM + blk * 16 + pj;

    #pragma unroll 1
    for (int s = 0; s < S_LEN; s++) {
        const ushort* hsrc = (s & 1) ? hb1 : hb0;
        ushort* hdst = (s & 1) ? hb0 : hb1;

        // prefetch gx[s] (independent of h) before the flag wait
        ushort2 gxr[4];
        {
            const ushort* gxs = gx + (size_t)s * BATCH * GDIM + gx_tb;
            #pragma unroll
            for (int g = 0; g < 4; g++)
                gxr[g] = *(const ushort2*)(gxs + g * 1024);
        }

        // wait for h_s: wave0 polls all 64 per-block flags in one wave load.
        // RELAXED+AGENT = sc1 load (IF/L3-coherent), no buffer_inv.
        if (s > 0) {
            if (wv == 0) {
                const unsigned* fl = flags + (size_t)s * 64;
                while (true) {
                    unsigned v = __hip_atomic_load(&fl[lane], __ATOMIC_RELAXED,
                                                   __HIP_MEMORY_SCOPE_AGENT);
                    if (__ballot(v != MAGIC) == 0ull) break;
                    __builtin_amdgcn_s_sleep(2);
                }
            }
            __syncthreads();
        }

        // gather full h into registers (sc1 8B loads -> fresh from IF/L3),
        // then stage to LDS. 32 x 8B per thread = 128 KiB total.
        {
            const unsigned long long* h64 = (const unsigned long long*)hsrc;
            unsigned long long hr[32];
            #pragma unroll
            for (int c = 0; c < 32; c++)
                hr[c] = __hip_atomic_load(&h64[c * 512 + tid], __ATOMIC_RELAXED,
                                          __HIP_MEMORY_SCOPE_AGENT);
            #pragma unroll
            for (int c = 0; c < 32; c++) {
                int u = c * 512 + tid;
                int row = u >> 8;
                int col = (u & 255) * 4;
                *(unsigned long long*)&Hs[row * HS2 + col] = hr[c];
            }
        }
        __syncthreads();

        // MFMA: gate-wave computes [mw*32..+32) x 16 over K=1024
        f32x4 acc0 = {0.f, 0.f, 0.f, 0.f};
        f32x4 acc1 = {0.f, 0.f, 0.f, 0.f};
        const int arow0 = (mw * 32 + l15) * HS2;
        const int arow1 = (mw * 32 + 16 + l15) * HS2;
        #pragma unroll
        for (int ks = 0; ks < 32; ks++) {
            const int ko = ks * 32 + quad * 8;
            bf16x8 a0 = *(const bf16x8*)&Hs[arow0 + ko];
            bf16x8 a1 = *(const bf16x8*)&Hs[arow1 + ko];
            acc0 = __builtin_amdgcn_mfma_f32_16x16x32_bf16(a0, wf[ks], acc0, 0, 0, 0);
            acc1 = __builtin_amdgcn_mfma_f32_16x16x32_bf16(a1, wf[ks], acc1, 0, 0, 0);
        }

        // exchange gates through LDS (C layout: col=lane&15, row=quad*4+reg)
        #pragma unroll
        for (int f = 0; f < 2; f++) {
            f32x4 a = f ? acc1 : acc0;
            int b0 = mw * 32 + f * 16 + quad * 4;
            #pragma unroll
            for (int r = 0; r < 4; r++)
                Gs[gate * (64 * GSB) + (b0 + r) * GSB + l15] = a[r];
        }
        __syncthreads();

        // pointwise: 2 elements per thread
        float hv[2], cv[2];
        #pragma unroll
        for (int u = 0; u < 2; u++) {
            float cold = u ? creg.y : creg.x;
            float g0 = Gs[0 * 64 * GSB + pb * GSB + pj + u] + bsum[0][u] + b2f(u ? gxr[0].y : gxr[0].x);
            float g1 = Gs[1 * 64 * GSB + pb * GSB + pj + u] + bsum[1][u] + b2f(u ? gxr[1].y : gxr[1].x);
            float g2 = Gs[2 * 64 * GSB + pb * GSB + pj + u] + bsum[2][u] + b2f(u ? gxr[2].y : gxr[2].x);
            float g3 = Gs[3 * 64 * GSB + pb * GSB + pj + u] + bsum[3][u] + b2f(u ? gxr[3].y : gxr[3].x);
            float ig = sigmoidf_(g0);
            float fg = sigmoidf_(g1);
            float gg = tanhf_(g2);
            float og = sigmoidf_(g3);
            float cn = fg * cold + ig * gg;
            float hn = og * tanhf_(cn);
            cv[u] = cn; hv[u] = hn;
        }
        creg.x = cv[0]; creg.y = cv[1];

        float2 ho; ho.x = hv[0]; ho.y = hv[1];
        *(float2*)&out[(size_t)s * BATCH * HDIM + (size_t)pb * HDIM + pcol] = ho;

        // publish h_{s+1}: sc1 write-through store (4B packed bf16x2)
        {
            unsigned hword = (unsigned)f2b(hv[0]) | ((unsigned)f2b(hv[1]) << 16);
            __hip_atomic_store((unsigned*)&hdst[(size_t)pb * HDIM + pcol], hword,
                               __ATOMIC_RELAXED, __HIP_MEMORY_SCOPE_AGENT);
        }

        if (s == S_LEN - 1) {
            float* tail = out + (size_t)S_LEN * BATCH * HDIM;
            *(float2*)&tail[(size_t)pb * HDIM + pcol] = ho;
            float2 co; co.x = cv[0]; co.y = cv[1];
            *(float2*)&tail[BATCH * HDIM + (size_t)pb * HDIM + pcol] = co;
        }

        // __syncthreads drains vmcnt(0): all sc1 h stores acked at the
        // coherence point before the flag store issues.
        __syncthreads();
        if (tid == 0) {
            asm volatile("s_waitcnt vmcnt(0)" ::: "memory");
            __hip_atomic_store(&flags[(size_t)(s + 1) * 64 + blk], MAGIC,
                               __ATOMIC_RELAXED, __HIP_MEMORY_SCOPE_AGENT);
        }
    }
}

extern "C" void kernel_launch(void* const* d_in, const int* in_sizes, int n_in,
                              void* d_out, int out_size, void* d_ws, size_t ws_size,
                              hipStream_t stream) {
    const float* x    = (const float*)d_in[0];
    const float* h0   = (const float*)d_in[1];
    const float* c0   = (const float*)d_in[2];
    const float* W_ih = (const float*)d_in[3];
    const float* b_ih = (const float*)d_in[4];
    const float* W_hh = (const float*)d_in[5];
    const float* b_hh = (const float*)d_in[6];
    float* out = (float*)d_out;

    const size_t n_x  = (size_t)S_LEN * BATCH * IDIM;
    const size_t n_w  = (size_t)GDIM * IDIM;
    const size_t o_xb    = 0;
    const size_t o_gx    = o_xb + n_x * 2;
    const size_t o_wih   = o_gx + (size_t)S_LEN * BATCH * GDIM * 2;
    const size_t o_whh   = o_wih + n_w * 2;
    const size_t o_bias  = o_whh + n_w * 2;
    const size_t o_h0    = o_bias + GDIM * 4;
    const size_t o_h1    = o_h0 + (size_t)BATCH * HDIM * 2;
    const size_t o_flags = o_h1 + (size_t)BATCH * HDIM * 2;
    const size_t flags_bytes = (size_t)(S_LEN + 1) * 64 * 4;
    const size_t total  = o_flags + flags_bytes;
    if (ws_size < total) return;

    char* ws = (char*)d_ws;
    ushort* xb   = (ushort*)(ws + o_xb);
    ushort* gx   = (ushort*)(ws + o_gx);
    ushort* wihb = (ushort*)(ws + o_wih);
    ushort* whhb = (ushort*)(ws + o_whh);
    float*  bias = (float*)(ws + o_bias);
    ushort* hb0  = (ushort*)(ws + o_h0);
    ushort* hb1  = (ushort*)(ws + o_h1);
    unsigned* flags = (unsigned*)(ws + o_flags);

    // conversions + bias + flag reset
    f2b_kernel<<<(int)(n_x / 1024), 256, 0, stream>>>(xb, x, (int)n_x);
    f2b_kernel<<<(int)(n_w / 1024), 256, 0, stream>>>(wihb, W_ih, (int)n_w);
    f2b_kernel<<<(int)(n_w / 1024), 256, 0, stream>>>(whhb, W_hh, (int)n_w);
    f2b_kernel<<<(BATCH * HDIM) / 1024, 256, 0, stream>>>(hb0, h0, BATCH * HDIM);
    bias_kernel<<<GDIM / 256, 256, 0, stream>>>(bias, b_ih, b_hh);
    hipMemsetAsync(flags, 0, flags_bytes, stream);

    // gates_x = x @ W_ih^T  (M=32768, N=4096, K=1024)
    {
        dim3 grid(GDIM / 128, (S_LEN * BATCH) / 128);
        gemm_bt_kernel<<<grid, 256, 0, stream>>>(xb, wihb, gx, S_LEN * BATCH, GDIM, IDIM);
    }

    // persistent recurrence (cooperative: all 64 blocks co-resident)
    {
        const ushort* gx_c = gx;
        const ushort* whh_c = whhb;
        const float* bias_c = bias;
        void* args[] = { (void*)&gx_c, (void*)&hb0, (void*)&hb1, (void*)&whh_c,
                         (void*)&bias_c, (void*)&c0, (void*)&out, (void*)&flags };
        hipLaunchCooperativeKernel((const void*)lstm_persistent, dim3(64), dim3(512),
                                   args, 0, stream);
    }
}